// Round 10
// baseline (106.494 us; speedup 1.0000x reference)
//
#include <hip/hip_runtime.h>

// QuantizeEMAReset forward (eval): VQ quantize + commit loss + perplexity/usage.
// z: [16,4096,64] fp32 -> N=65536 tokens, C=64. codebook: [1024,64] fp32.
// out: [z_q_bar (4194304 f32), commit_loss, ppl, usage] flat.
//
// R10: R9 + (a) MARGIN 1e-3 -> 4e-3 (R9's absmax 6.0 = argmin flips escaping
// the rescue; fp16-split worst-case distance error ~1.4e-3 > old margin) and
// (b) 4-tile groups per barrier phase: 16 barriers/block instead of 64
// (R9: MfmaUtil 10%, VALUBusy 19% -> barrier-convoy-bound). 3-slot group ring
// (48KB), vmcnt(4) counted waits, DMA for group p+2 issued right after the
// barrier (slot (p+2)%3 != p%3, != (p+1)%3; lagging-wave reads of (p-1)%3
// are drained before the barrier by their MFMA consumption).
//
// ws float-index map:
//   [0,1024)      cnorm
//   [1024,2048)   counts
//   [2048,2560)   loss partials (512 blocks)
//   [8192,73728)  cbhl tile stream: 64 tiles x 2048 halves (hi 1KB | lo 1KB)

typedef _Float16 half8 __attribute__((ext_vector_type(8)));
typedef float f32x4 __attribute__((ext_vector_type(4)));

#define NTOK 65536
#define KCODE 1024
#define OUT_SCALARS 4194304
#define MARGIN 4e-3f

#define WS_CNT   1024
#define WS_LOSS  2048
#define WS_CBHL  8192

static __device__ __forceinline__ unsigned int order_key(float f) {
    unsigned int u = __float_as_uint(f);
    unsigned int mask = (u >> 31) ? 0xFFFFFFFFu : 0x80000000u;
    return u ^ mask;   // monotone: a<b (float) <=> key(a)<key(b) (uint)
}

__global__ void prep_kernel(const float* __restrict__ cb, float* __restrict__ ws) {
    const int k = blockIdx.x * 256 + threadIdx.x;   // 0..1023
    const float4* cb4 = (const float4*)cb;
    float s = 0.f;
#pragma unroll
    for (int j = 0; j < 16; ++j) {
        float4 v = cb4[k * 16 + j];
        s = fmaf(v.x, v.x, s);
        s = fmaf(v.y, v.y, s);
        s = fmaf(v.z, v.z, s);
        s = fmaf(v.w, v.w, s);
    }
    ws[k] = s;             // cnorm: exact R1 chain
    ws[WS_CNT + k] = 0.f;  // zero histogram

    // swizzled tile stream: tile = k>>4, c = k&15
    _Float16* base = (_Float16*)(ws + WS_CBHL) + (size_t)(k >> 4) * 2048 + (k & 15) * 64;
    const int c = k & 15;
#pragma unroll
    for (int d8 = 0; d8 < 8; ++d8) {
        float4 a = cb4[k * 16 + 2 * d8], b = cb4[k * 16 + 2 * d8 + 1];
        float xf[8] = {a.x, a.y, a.z, a.w, b.x, b.y, b.z, b.w};
        half8 h, lo;
#pragma unroll
        for (int i = 0; i < 8; ++i) {
            _Float16 hi = (_Float16)xf[i];
            h[i] = hi;
            lo[i] = (_Float16)((xf[i] - (float)hi) * 4096.f);  // scaled: no f16 denorm flush
        }
        const int pos = ((d8 + c) & 7) * 8;   // 16B-slot rotation (bank spread)
        *(half8*)(base + pos) = h;
        *(half8*)(base + 1024 + pos) = lo;
    }
}

__launch_bounds__(256, 2)
__global__ void quant_kernel(const float* __restrict__ z,
                             const float* __restrict__ cb,
                             float* __restrict__ out,
                             float* __restrict__ ws) {
    const int t = threadIdx.x, blk = blockIdx.x;
    const int w = t >> 6, l = t & 63;
    const int cl = l & 15, g = l >> 4;
    const int tokW = blk * 128 + w * 32;    // wave's first token (2 sets of 16)

    __shared__ __align__(16) _Float16 tiles[3][4][2048];  // 3-slot group ring, 48KB
    __shared__ __align__(16) float cn_lds[1024];
    __shared__ int win[128];
    __shared__ float lsum[128];

    // ---- stage cnorm to LDS ----
    *(float4*)&cn_lds[t * 4] = *(const float4*)(ws + t * 4);

    // ---- B fragments: 2 token sets of 16 (persistent regs) ----
    half8 zh0[2], zl0[2], zh1[2], zl1[2];
#define MKFRAG(ZH, ZL, TOK)                                                \
    {                                                                      \
        const float4* z4 = (const float4*)z + (size_t)(TOK) * 16;          \
        _Pragma("unroll")                                                  \
        for (int q = 0; q < 2; ++q) {                                      \
            float4 a = z4[2 * g + 8 * q], b = z4[2 * g + 8 * q + 1];       \
            float xf[8] = {a.x, a.y, a.z, a.w, b.x, b.y, b.z, b.w};        \
            _Pragma("unroll")                                              \
            for (int i = 0; i < 8; ++i) {                                  \
                _Float16 h = (_Float16)xf[i];                              \
                ZH[q][i] = h;                                              \
                ZL[q][i] = (_Float16)((xf[i] - (float)h) * 4096.f);        \
            }                                                              \
        }                                                                  \
    }
    MKFRAG(zh0, zl0, tokW + cl)
    MKFRAG(zh1, zl1, tokW + 16 + cl)
#undef MKFRAG

    // PIN: all z-loads + LDS writes complete; nothing crosses this point.
    // In-loop vmcnt then counts ONLY the global_load_lds DMA stream.
    asm volatile("s_waitcnt vmcnt(0) lgkmcnt(0)" ::: "memory");
    __builtin_amdgcn_sched_barrier(0);

    // per-wave DMA src: wave w stages quarter w of each tile (1KB DMA/tile)
    const char* dma_src = (const char*)(ws + WS_CBHL) + w * 1024 + l * 16;
    const int rot = (g + cl) & 7;
    const int o0 = cl * 64 + rot * 8;
    const int o1 = cl * 64 + (rot ^ 4) * 8;

    // prologue: groups 0 and 1 in flight (8 DMAs/wave)
#pragma unroll
    for (int p = 0; p < 2; ++p)
#pragma unroll
        for (int q = 0; q < 4; ++q)
            __builtin_amdgcn_global_load_lds(
                (const __attribute__((address_space(1))) void*)(dma_src + (p * 4 + q) * 4096),
                (__attribute__((address_space(3))) void*)&tiles[p][q][w * 512], 16, 0, 0);

    float d1a = 3.4e38f, d2a = 3.4e38f, d1b = 3.4e38f, d2b = 3.4e38f;
    int idxa = 0, idxb = 0;

#define ARGMIN(A1, A2, A3, D1, D2, IDX, ti)                                 \
    _Pragma("unroll")                                                       \
    for (int r = 0; r < 4; ++r) {                                           \
        float dot = fmaf(A2[r] + A3[r], 2.44140625e-4f, A1[r]);             \
        float d = fmaf(-2.f, dot, cna[r]);                                  \
        const int kidx = (ti) * 16 + 4 * g + r;                             \
        bool lt = d < D1;                                                   \
        D2 = fminf(D2, fmaxf(d, D1));                                       \
        IDX = lt ? kidx : IDX;                                              \
        D1 = fminf(D1, d);                                                  \
    }

#define TILE_COMPUTE(ti, TP)                                                          \
    {                                                                                 \
        const _Float16* tp = (TP);                                                    \
        half8 H0 = *(const half8*)(tp + o0);                                          \
        half8 H1 = *(const half8*)(tp + o1);                                          \
        half8 L0 = *(const half8*)(tp + 1024 + o0);                                   \
        half8 L1 = *(const half8*)(tp + 1024 + o1);                                   \
        float4 cnv = *(const float4*)&cn_lds[(ti) * 16 + 4 * g];                      \
        const float cna[4] = {cnv.x, cnv.y, cnv.z, cnv.w};                            \
        f32x4 p1a = {0.f,0.f,0.f,0.f}, p2a = {0.f,0.f,0.f,0.f}, p3a = {0.f,0.f,0.f,0.f}; \
        f32x4 p1b = {0.f,0.f,0.f,0.f}, p2b = {0.f,0.f,0.f,0.f}, p3b = {0.f,0.f,0.f,0.f}; \
        p1a = __builtin_amdgcn_mfma_f32_16x16x32_f16(H0, zh0[0], p1a, 0, 0, 0);       \
        p1a = __builtin_amdgcn_mfma_f32_16x16x32_f16(H1, zh0[1], p1a, 0, 0, 0);       \
        p1b = __builtin_amdgcn_mfma_f32_16x16x32_f16(H0, zh1[0], p1b, 0, 0, 0);       \
        p1b = __builtin_amdgcn_mfma_f32_16x16x32_f16(H1, zh1[1], p1b, 0, 0, 0);       \
        p2a = __builtin_amdgcn_mfma_f32_16x16x32_f16(H0, zl0[0], p2a, 0, 0, 0);       \
        p2a = __builtin_amdgcn_mfma_f32_16x16x32_f16(H1, zl0[1], p2a, 0, 0, 0);       \
        p2b = __builtin_amdgcn_mfma_f32_16x16x32_f16(H0, zl1[0], p2b, 0, 0, 0);       \
        p2b = __builtin_amdgcn_mfma_f32_16x16x32_f16(H1, zl1[1], p2b, 0, 0, 0);       \
        p3a = __builtin_amdgcn_mfma_f32_16x16x32_f16(L0, zh0[0], p3a, 0, 0, 0);       \
        p3a = __builtin_amdgcn_mfma_f32_16x16x32_f16(L1, zh0[1], p3a, 0, 0, 0);       \
        p3b = __builtin_amdgcn_mfma_f32_16x16x32_f16(L0, zh1[0], p3b, 0, 0, 0);       \
        p3b = __builtin_amdgcn_mfma_f32_16x16x32_f16(L1, zh1[1], p3b, 0, 0, 0);       \
        ARGMIN(p1a, p2a, p3a, d1a, d2a, idxa, ti)                                     \
        ARGMIN(p1b, p2b, p3b, d1b, d2b, idxb, ti)                                     \
    }

    // phase P: wait own group-P DMAs (vmcnt), barrier, issue group P+2, compute 4 tiles.
#define GROUP_BODY(P, SLOT, SLOT2, VM, ISSUE)                                         \
    {                                                                                 \
        asm volatile("s_waitcnt vmcnt(" VM ")" ::: "memory");                         \
        asm volatile("s_barrier" ::: "memory");                                       \
        if (ISSUE) {                                                                  \
            _Pragma("unroll")                                                         \
            for (int q = 0; q < 4; ++q)                                               \
                __builtin_amdgcn_global_load_lds(                                     \
                    (const __attribute__((address_space(1))) void*)(dma_src + (((P) + 2) * 4 + q) * 4096), \
                    (__attribute__((address_space(3))) void*)&tiles[SLOT2][q][w * 512], \
                    16, 0, 0);                                                        \
        }                                                                             \
        TILE_COMPUTE((P) * 4 + 0, &tiles[SLOT][0][0])                                 \
        TILE_COMPUTE((P) * 4 + 1, &tiles[SLOT][1][0])                                 \
        TILE_COMPUTE((P) * 4 + 2, &tiles[SLOT][2][0])                                 \
        TILE_COMPUTE((P) * 4 + 3, &tiles[SLOT][3][0])                                 \
    }

    // phases 0..14 (5 x 3, static ring slots), issue while P+2 <= 15
    for (int i3 = 0; i3 < 15; i3 += 3) {
        GROUP_BODY(i3 + 0, 0, 2, "4", (i3 + 0) <= 13)
        GROUP_BODY(i3 + 1, 1, 0, "4", (i3 + 1) <= 13)
        GROUP_BODY(i3 + 2, 2, 1, "4", (i3 + 2) <= 13)
    }
    GROUP_BODY(15, 0, 0, "0", 0)   // last group
#undef GROUP_BODY
#undef TILE_COMPUTE
#undef ARGMIN

    // ---- merge 4 lanes per token (xor 16, 32) for each set ----
#define MERGE(D1, D2, KEY)                                                  \
    _Pragma("unroll")                                                       \
    for (int off = 16; off <= 32; off <<= 1) {                              \
        unsigned long long ok = __shfl_xor(KEY, off, 64);                   \
        float od1 = __shfl_xor(D1, off, 64);                                \
        float od2 = __shfl_xor(D2, off, 64);                                \
        D2 = fminf(fminf(D2, od2), fmaxf(D1, od1));                         \
        D1 = fminf(D1, od1);                                                \
        KEY = ok < KEY ? ok : KEY;                                          \
    }
    unsigned long long keyA = ((unsigned long long)order_key(d1a) << 32) | (unsigned)idxa;
    unsigned long long keyB = ((unsigned long long)order_key(d1b) << 32) | (unsigned)idxb;
    MERGE(d1a, d2a, keyA)
    MERGE(d1b, d2b, keyB)
#undef MERGE
    int fidxA = (int)(unsigned)(keyA & 0xFFFFFFFFull);
    int fidxB = (int)(unsigned)(keyB & 0xFFFFFFFFull);

    // ---- in-wave exact fp32 rescue for near-ties (rare) ----
    unsigned long long mask =
        (__ballot((l < 16) && (d2a - d1a < MARGIN)) & 0xFFFFull) |
        ((__ballot((l < 16) && (d2b - d1b < MARGIN)) & 0xFFFFull) << 16);
    while (mask) {
        const int b = __ffsll((long long)mask) - 1;   // wave-uniform
        mask &= mask - 1;
        const int tokR = tokW + b;                    // b<16: set A; else set B
        const float4* zr = (const float4*)z + (size_t)tokR * 16;
        float4 xv[16];
#pragma unroll
        for (int j = 0; j < 16; ++j) xv[j] = zr[j];   // broadcast load
        unsigned long long bk = ~0ull;
#pragma unroll 4
        for (int q = 0; q < 16; ++q) {
            const int k = l + q * 64;
            const float4* cr = (const float4*)cb + (size_t)k * 16;
            float s = 0.f;
#pragma unroll
            for (int j = 0; j < 16; ++j) {
                float4 c = cr[j];
                s = fmaf(xv[j].x, c.x, s);
                s = fmaf(xv[j].y, c.y, s);
                s = fmaf(xv[j].z, c.z, s);
                s = fmaf(xv[j].w, c.w, s);
            }
            float d = fmaf(-2.f, s, cn_lds[k]);   // exact R1 distance
            unsigned long long kk = ((unsigned long long)order_key(d) << 32) | (unsigned)k;
            bk = kk < bk ? kk : bk;
        }
#pragma unroll
        for (int off = 1; off < 64; off <<= 1) {
            unsigned long long o = __shfl_xor(bk, off, 64);
            bk = o < bk ? o : bk;
        }
        const int ni = (int)(unsigned)(bk & 0xFFFFFFFFull);
        if (l == (b & 15)) {
            if (b < 16) fidxA = ni; else fidxB = ni;
        }
    }

    // ---- commit winners ----
    if (l < 16) {
        win[w * 32 + l] = fidxA;
        win[w * 32 + 16 + l] = fidxB;
        atomicAdd(&ws[WS_CNT + fidxA], 1.f);   // integer-valued: exact, order-indep
        atomicAdd(&ws[WS_CNT + fidxB], 1.f);
    }
    __syncthreads();

    // ---- fused epilogue: z_q_bar + commit-loss partial (z re-read, L2-hot) ----
    {
        const int lt = t >> 1, h = t & 1;       // 2 threads per token
        const int tokE = blk * 128 + lt;
        const int idx = win[lt];
        const float4* zr = (const float4*)z + (size_t)tokE * 16 + h * 8;
        const float4* cq = (const float4*)cb + (size_t)idx * 16 + h * 8;
        float4* o4 = (float4*)out + (size_t)tokE * 16 + h * 8;
        float ss = 0.f;
#pragma unroll
        for (int j = 0; j < 8; ++j) {
            float4 xvv = zr[j];
            float4 qv = cq[j];
            float4 ov; float dx;
            dx = qv.x - xvv.x; ov.x = xvv.x + dx; ss = fmaf(dx, dx, ss);
            dx = qv.y - xvv.y; ov.y = xvv.y + dx; ss = fmaf(dx, dx, ss);
            dx = qv.z - xvv.z; ov.z = xvv.z + dx; ss = fmaf(dx, dx, ss);
            dx = qv.w - xvv.w; ov.w = xvv.w + dx; ss = fmaf(dx, dx, ss);
            o4[j] = ov;
        }
        float os = __shfl_down(ss, 1, 64);      // partner lane (same token)
        if (h == 0) lsum[lt] = (ss + os) * (1.f / 64.f);
    }
    __syncthreads();
    if (t < 64) {
        float v = lsum[t] + lsum[t + 64];
#pragma unroll
        for (int off = 32; off > 0; off >>= 1) v += __shfl_down(v, off, 64);
        if (t == 0) ws[WS_LOSS + blk] = v;
    }
}

__global__ void final_kernel(const float* __restrict__ ws, float* __restrict__ out) {
    __shared__ float red[1024];
    const int t = threadIdx.x;
    const float c = ws[WS_CNT + t];

    red[t] = c; __syncthreads();
    for (int s = 512; s > 0; s >>= 1) { if (t < s) red[t] += red[t + s]; __syncthreads(); }
    const float total = fmaxf(red[0], 1e-6f);
    __syncthreads();

    const float p = c / total;
    red[t] = p * logf(p + 1e-7f); __syncthreads();
    for (int s = 512; s > 0; s >>= 1) { if (t < s) red[t] += red[t + s]; __syncthreads(); }
    const float ent = red[0];
    __syncthreads();

    red[t] = (c >= 1.f) ? 1.f : 0.f; __syncthreads();
    for (int s = 512; s > 0; s >>= 1) { if (t < s) red[t] += red[t + s]; __syncthreads(); }
    const float used = red[0];
    __syncthreads();

    red[t] = (t < 512) ? ws[WS_LOSS + t] : 0.f;   // 512 block partials
    __syncthreads();
    for (int s = 512; s > 0; s >>= 1) { if (t < s) red[t] += red[t + s]; __syncthreads(); }

    if (t == 0) {
        out[OUT_SCALARS + 0] = red[0] * (1.f / (float)NTOK);
        out[OUT_SCALARS + 1] = expf(-ent);
        out[OUT_SCALARS + 2] = used * (1.f / (float)KCODE);
    }
}

extern "C" void kernel_launch(void* const* d_in, const int* in_sizes, int n_in,
                              void* d_out, int out_size, void* d_ws, size_t ws_size,
                              hipStream_t stream) {
    const float* z  = (const float*)d_in[0];
    const float* cb = (const float*)d_in[1];
    float* out = (float*)d_out;
    float* ws  = (float*)d_ws;   // ~295 KB used

    prep_kernel <<<4, 256, 0, stream>>>(cb, ws);
    quant_kernel<<<NTOK / 128, 256, 0, stream>>>(z, cb, out, ws);
    final_kernel<<<1, 1024, 0, stream>>>(ws, out);
}